// Round 2
// baseline (795.911 us; speedup 1.0000x reference)
//
#include <hip/hip_runtime.h>
#include <hip/hip_bf16.h>
#include <stdint.h>

// Problem constants (compile-time; shapes fixed by setup_inputs()).
#define M_ROWS 4096      // batch rows of x
#define IN_F   4096      // K
#define OUT_F  11008     // N
#define N_GROUPS 32      // IN_F / 128
#define ALPHA  0.05f

typedef __bf16 bf16;
typedef __bf16 bf16x8 __attribute__((ext_vector_type(8)));
typedef float  floatx16 __attribute__((ext_vector_type(16)));

// async global->LDS, 16B per lane; LDS dest = wave-uniform base + lane*16
__device__ __forceinline__ void async_copy16(const void* g, void* l) {
  __builtin_amdgcn_global_load_lds(
      (const __attribute__((address_space(1))) void*)g,
      (__attribute__((address_space(3))) void*)l, 16, 0, 0);
}

// ---------------------------------------------------------------------------
// Phase 1 (fused): grid-strided, 2048 blocks (G11 memory-bound recipe).
//  chunk idx < W_CH  : wn[o,i..i+7]  = dequant+noise -> bf16
//  chunk idx >= W_CH : xb[j..j+7]    = x fp32 -> bf16
// Previous version used 22016+8192 one-shot blocks (48 B/thread) across two
// launches; phase-1 ran ~4x off its ~100 us streaming floor. Grid-stride at
// 8 blocks/CU amortizes per-block overhead; access pattern unchanged
// (consecutive threads -> consecutive 16 B chunks).
// ---------------------------------------------------------------------------
__global__ __launch_bounds__(256) void prep_kernel(
    const float* __restrict__ x, const int* __restrict__ q,
    const float* __restrict__ scales, const float* __restrict__ zeros,
    const float* __restrict__ noise, bf16* __restrict__ wn,
    bf16* __restrict__ xb) {
  const int W_CH = OUT_F * (IN_F >> 3);              // 5,636,096 weight chunks
  const int T_CH = W_CH + (M_ROWS * (IN_F >> 3));    // + 2,097,152 x chunks
  const int stride = gridDim.x * 256;
  for (int idx = blockIdx.x * 256 + threadIdx.x; idx < T_CH; idx += stride) {
    if (idx < W_CH) {
      int o = idx >> 9;                  // 512 chunks per output row
      int i = (idx & 511) << 3;          // 8-aligned -> single group
      int g = i >> 7;
      float s = scales[o * N_GROUPS + g];
      float z = zeros[o * N_GROUPS + g];
      size_t base = (size_t)o * IN_F + i;
      int4   q0 = *(const int4*)(q + base);
      int4   q1 = *(const int4*)(q + base + 4);
      float4 n0 = *(const float4*)(noise + base);
      float4 n1 = *(const float4*)(noise + base + 4);
      float qs[8] = {(float)q0.x, (float)q0.y, (float)q0.z, (float)q0.w,
                     (float)q1.x, (float)q1.y, (float)q1.z, (float)q1.w};
      float ns[8] = {n0.x, n0.y, n0.z, n0.w, n1.x, n1.y, n1.z, n1.w};
      bf16x8 outv;
#pragma unroll
      for (int j = 0; j < 8; ++j) {
        float w = (qs[j] - z) * s;
        float v = fmaf(ALPHA * fabsf(w), ns[j], w);   // w + noise*ALPHA*|w|
        outv[j] = (bf16)v;
      }
      *(bf16x8*)(wn + base) = outv;
    } else {
      size_t base = (size_t)(idx - W_CH) << 3;
      float4 a0 = *(const float4*)(x + base);
      float4 a1 = *(const float4*)(x + base + 4);
      float vs[8] = {a0.x, a0.y, a0.z, a0.w, a1.x, a1.y, a1.z, a1.w};
      bf16x8 outv;
#pragma unroll
      for (int j = 0; j < 8; ++j) outv[j] = (bf16)vs[j];
      *(bf16x8*)(xb + base) = outv;
    }
  }
}

// ---------------------------------------------------------------------------
// Phase 2: 256x256-tile 8-phase GEMM, 32x32x16 MFMA core.
//
// Same ring/vmcnt/swizzle structure as the verified 16x16 version (round 1,
// passed, SQ_LDS_BANK_CONFLICT = 0); only the compute core changed:
//  - each wave's 128x64 C tile = 4(mt) x 2(nt) tiles of 32x32;
//    acc = 4*2*16 = 128 fp32 regs (unchanged total).
//  - per K=32 pair-slot: 2 phases (k-half h=0,1), each {6 ds_read_b128,
//    2 gload_lds stage, barrier, lgkmcnt(0), 8 MFMA 32x32x16, barrier}.
//  - 32x32 pipe ceiling 2382-2495 TF vs 16x16's 2075; half the MFMA instrs.
//
// Operand layouts (32x32x16 bf16):
//  A/B: lane l holds row (A) / col (B) = l&31, k = (l>>5)*8 + j  (8 bf16).
//  C/D (m74/m101-verified): col = lane&31, row = (reg&3)+8*(reg>>2)+4*(lane>>5).
//
// LDS swizzle (unchanged): logical (row r, 8-elem chunk kc) lives at elem
// (r>>1)*64 + pc*8, pc = (((r&1)<<2)|kc) ^ ((r>>1)&7). Staging realizes it by
// pre-permuting each lane's GLOBAL source chunk (LDS dest linear; verified:
// dest pc = dec^(ln>>3) = ln&7). Fragment read (32x32): kc = h*2 + (ln>>5),
// row&1 = ln&1, (row>>1)&7 = ((ln&31)>>1)&7 -> every 8-lane service group
// hits all 8 bank-groups exactly once (k-half 1 offset = k-half 0 ^ 16 elems).
// ---------------------------------------------------------------------------
__global__ __launch_bounds__(512, 2) void gemm_8ph_kernel(
    const bf16* __restrict__ A,    // [M_ROWS][IN_F]
    const bf16* __restrict__ W,    // [OUT_F][IN_F]
    const float* __restrict__ bias,
    float* __restrict__ C) {       // [M_ROWS][OUT_F]
  __shared__ bf16 lds[4 * 16384];  // 4 pair-slots x (A 8192 + B 8192) elems

  const int tid = threadIdx.x;
  const int wv = tid >> 6;          // wave 0..7
  const int ln = tid & 63;
  const int wr = wv >> 2;           // wave M row (0..1) -> rows wr*128..+128
  const int wc = wv & 3;            // wave N col (0..3) -> cols wc*64..+64

  // XCD-bijective swizzle (688 = 8*86) + m-pair supertile: each XCD sweeps
  // bn with 2 resident A panels (4 MB, L2-fits); all XCDs share B via L3.
  const int orig = blockIdx.x;
  const int idx  = orig >> 3;                    // 0..85
  const int bm   = ((orig & 7) << 1) | (idx & 1);
  const int bn   = idx >> 1;
  const int mbase = bm << 8;
  const int nbase = bn << 8;

  // Staging source (per-lane pre-swizzled global address; LDS dest linear).
  const int dec    = (ln & 7) ^ (ln >> 3);
  const int rstage = wv * 32 + (ln >> 3) * 2 + (dec >> 2);  // j=0 row; j=1 +16
  const int kcol   = (dec & 3) * 8;
  const bf16* aS = A + (size_t)(mbase + rstage) * IN_F + kcol;
  const bf16* bS = W + (size_t)(nbase + rstage) * IN_F + kcol;

  // Fragment ds_read offsets (elements), k-half 0; k-half 1 = ^16.
  const int l31 = ln & 31;
  const int g2  = ln >> 5;
  const int pc  = (((ln & 1) << 2) | g2) ^ ((l31 >> 1) & 7);
  const int aoff0 =        (wr * 64 + (l31 >> 1)) * 64 + pc * 8;  // + mt*1024
  const int boff0 = 8192 + (wc * 32 + (l31 >> 1)) * 64 + pc * 8;  // + nt*1024

  floatx16 acc[4][2] = {};

#define STAGE_A(DST, KH)                                                          \
  do {                                                                            \
    async_copy16(aS + (size_t)(KH) * 32,             &lds[(DST) * 16384 + wv * 1024]);        \
    async_copy16(aS + (size_t)(KH) * 32 + 16 * IN_F, &lds[(DST) * 16384 + wv * 1024 + 512]);  \
  } while (0)
#define STAGE_B(DST, KH)                                                          \
  do {                                                                            \
    async_copy16(bS + (size_t)(KH) * 32,             &lds[(DST) * 16384 + 8192 + wv * 1024]);       \
    async_copy16(bS + (size_t)(KH) * 32 + 16 * IN_F, &lds[(DST) * 16384 + 8192 + wv * 1024 + 512]); \
  } while (0)

  // Prologue: stage P0,P1,P2 (12 loads). vmcnt(8) -> oldest 4 (P0) landed.
  STAGE_A(0, 0); STAGE_B(0, 0);
  STAGE_A(1, 1); STAGE_B(1, 1);
  STAGE_A(2, 2); STAGE_B(2, 2);
  asm volatile("s_waitcnt vmcnt(8)" ::: "memory");
  __builtin_amdgcn_s_barrier();

#define PAIR(SLOT, KH, DO_STAGE, TVM)                                             \
  {                                                                               \
    bf16x8 af[4], bq[2];                                                          \
    _Pragma("unroll") for (int mt = 0; mt < 4; ++mt)                              \
      af[mt] = *(const bf16x8*)&lds[(SLOT) * 16384 + aoff0 + mt * 1024];          \
    _Pragma("unroll") for (int nt = 0; nt < 2; ++nt)                              \
      bq[nt] = *(const bf16x8*)&lds[(SLOT) * 16384 + boff0 + nt * 1024];          \
    if (DO_STAGE) STAGE_A(((SLOT) + 3) & 3, (KH) + 3);                            \
    __builtin_amdgcn_s_barrier();                                                 \
    asm volatile("s_waitcnt lgkmcnt(0)" ::: "memory");                            \
    __builtin_amdgcn_s_setprio(1);                                                \
    _Pragma("unroll") for (int mt = 0; mt < 4; ++mt)                              \
      _Pragma("unroll") for (int nt = 0; nt < 2; ++nt)                            \
        acc[mt][nt] = __builtin_amdgcn_mfma_f32_32x32x16_bf16(                    \
            af[mt], bq[nt], acc[mt][nt], 0, 0, 0);                                \
    __builtin_amdgcn_s_setprio(0);                                                \
    __builtin_amdgcn_s_barrier();                                                 \
    _Pragma("unroll") for (int mt = 0; mt < 4; ++mt)                              \
      af[mt] = *(const bf16x8*)&lds[(SLOT) * 16384 + ((aoff0 ^ 16) + mt * 1024)]; \
    _Pragma("unroll") for (int nt = 0; nt < 2; ++nt)                              \
      bq[nt] = *(const bf16x8*)&lds[(SLOT) * 16384 + ((boff0 ^ 16) + nt * 1024)]; \
    if (DO_STAGE) STAGE_B(((SLOT) + 3) & 3, (KH) + 3);                            \
    __builtin_amdgcn_s_barrier();                                                 \
    asm volatile("s_waitcnt lgkmcnt(0)" ::: "memory");                            \
    __builtin_amdgcn_s_setprio(1);                                                \
    _Pragma("unroll") for (int mt = 0; mt < 4; ++mt)                              \
      _Pragma("unroll") for (int nt = 0; nt < 2; ++nt)                            \
        acc[mt][nt] = __builtin_amdgcn_mfma_f32_32x32x16_bf16(                    \
            af[mt], bq[nt], acc[mt][nt], 0, 0, 0);                                \
    __builtin_amdgcn_s_setprio(0);                                                \
    asm volatile("s_waitcnt " TVM ::: "memory");                                  \
    __builtin_amdgcn_s_barrier();                                                 \
  }

  // Main loop: 31 ring revolutions (pairs 0..123), all staging P_{n+3}.
  for (int kh = 0; kh < 124; kh += 4) {
    PAIR(0, kh + 0, true, "vmcnt(8)");
    PAIR(1, kh + 1, true, "vmcnt(8)");
    PAIR(2, kh + 2, true, "vmcnt(8)");
    PAIR(3, kh + 3, true, "vmcnt(8)");
  }
  // Tail: pair 124 still stages P_127; then drain 8 -> 4 -> 0.
  PAIR(0, 124, true,  "vmcnt(8)");
  PAIR(1, 125, false, "vmcnt(4)");
  PAIR(2, 126, false, "vmcnt(0)");
  PAIR(3, 127, false, "vmcnt(0)");

#undef PAIR
#undef STAGE_A
#undef STAGE_B

  // Epilogue. 32x32 C/D layout: col = lane&31, row = (reg&3)+8*(reg>>2)+4*g2.
#pragma unroll
  for (int nt = 0; nt < 2; ++nt) {
    int n = nbase + wc * 64 + nt * 32 + l31;
    float bv = bias[n];
#pragma unroll
    for (int mt = 0; mt < 4; ++mt) {
      int mb2 = mbase + wr * 128 + mt * 32 + 4 * g2;
#pragma unroll
      for (int r = 0; r < 16; ++r) {
        int m = mb2 + (r & 3) + 8 * (r >> 2);
        C[(size_t)m * OUT_F + n] = acc[mt][nt][r] + bv;
      }
    }
  }
}

// ---------------------------------------------------------------------------
extern "C" void kernel_launch(void* const* d_in, const int* in_sizes, int n_in,
                              void* d_out, int out_size, void* d_ws, size_t ws_size,
                              hipStream_t stream) {
  const float* x       = (const float*)d_in[0];  // [4096][4096]
  const int*   qweight = (const int*)d_in[1];    // [11008][4096]
  const float* scales  = (const float*)d_in[2];  // [11008][32]
  const float* zeros   = (const float*)d_in[3];  // [11008][32]
  const float* bias    = (const float*)d_in[4];  // [11008]
  const float* noise   = (const float*)d_in[5];  // [11008][4096]
  float* out = (float*)d_out;                    // [4096][11008]

  // Workspace layout: wn bf16 [OUT_F][IN_F] (90.2 MB), then xb bf16 (33.6 MB).
  bf16* wn = (bf16*)d_ws;
  bf16* xb = (bf16*)((char*)d_ws + (size_t)OUT_F * IN_F * sizeof(bf16));

  // Phase 1: fused dequant+noise+xcast, grid-strided at 8 blocks/CU.
  prep_kernel<<<2048, 256, 0, stream>>>(x, qweight, scales, zeros, noise, wn, xb);

  // Phase 2: 256x256-tile 8-phase bf16 MFMA GEMM (32x32x16 core).
  // Grid: (11008/256)*(4096/256) = 43*16 = 688 = 8 XCDs * 86.
  gemm_8ph_kernel<<<dim3(688), 512, 0, stream>>>(xb, wn, bias, out);
}